// Round 4
// baseline (1170.922 us; speedup 1.0000x reference)
//
#include <hip/hip_runtime.h>

// ---------------------------------------------------------------------------
// OptimEDM: denoised = softmax(-||x-y||^2 / 2s^2) @ y
// Round 4: 32x32x16 MFMA in QK/PV (half the instr count, higher ceiling);
//          stage-before-MFMA body; prep_y fused with transpose (yT);
//          softmax 2-pass with deferred normalization (PV scales by 1/sum).
// ---------------------------------------------------------------------------

typedef __attribute__((ext_vector_type(4))) float f32x4;
typedef __attribute__((ext_vector_type(16))) float f32x16;
typedef __attribute__((ext_vector_type(4))) unsigned short u16x4;
typedef __attribute__((ext_vector_type(8))) unsigned short u16x8;
typedef __attribute__((ext_vector_type(8))) __bf16 bf16x8;

#define NREAL 50000
#define NP    50176   // 392 * 128
#define DD    3072
#define BB    512

#define WAIT8  asm volatile("s_waitcnt vmcnt(8)" ::: "memory")
#define WAIT0  asm volatile("s_waitcnt vmcnt(0)" ::: "memory")
#define LGKM0  asm volatile("s_waitcnt lgkmcnt(0)" ::: "memory")
#define BAR    __builtin_amdgcn_s_barrier()
#define SCHED0 __builtin_amdgcn_sched_barrier(0)

__device__ __forceinline__ unsigned short f32_bf16_rne(float f) {
  unsigned int u = __float_as_uint(f);
  unsigned int r = 0x7FFFu + ((u >> 16) & 1u);
  return (unsigned short)((u + r) >> 16);
}
__device__ __forceinline__ float bf16_f32(unsigned short h) {
  return __uint_as_float(((unsigned int)h) << 16);
}
__device__ __forceinline__ void gload16(const unsigned short* g, unsigned short* l) {
  __builtin_amdgcn_global_load_lds(
      (const __attribute__((address_space(1))) void*)g,
      (__attribute__((address_space(3))) void*)l, 16, 0, 0);
}
__device__ __forceinline__ bf16x8 ldsld(const unsigned short* p) {
  return __builtin_bit_cast(bf16x8, *(const u16x8*)p);
}

__global__ __launch_bounds__(256) void zero_kernel(f32x4* p) {
  p[(size_t)blockIdx.x * 256 + threadIdx.x] = (f32x4){0.f, 0.f, 0.f, 0.f};
}

__global__ __launch_bounds__(256) void prep_x_kernel(
    const float* __restrict__ x, const float* __restrict__ sigma,
    unsigned short* __restrict__ xhi, unsigned short* __restrict__ xlo,
    float* __restrict__ x2, float* __restrict__ inv2s2) {
  const int b = blockIdx.x, t = threadIdx.x;
  const f32x4* xr = (const f32x4*)(x + (size_t)b * DD);
  float ssq = 0.f;
#pragma unroll
  for (int i = 0; i < 3; ++i) {
    const int idx = i * 256 + t;
    f32x4 v = xr[idx];
    u16x4 h, l;
#pragma unroll
    for (int j = 0; j < 4; ++j) {
      float f = v[j];
      ssq += f * f;
      unsigned short hb = f32_bf16_rne(f);
      h[j] = hb;
      l[j] = f32_bf16_rne(f - bf16_f32(hb));
    }
    *(u16x4*)(xhi + (size_t)b * DD + idx * 4) = h;
    *(u16x4*)(xlo + (size_t)b * DD + idx * 4) = l;
  }
  __shared__ float red[4];
#pragma unroll
  for (int off = 32; off > 0; off >>= 1) ssq += __shfl_xor(ssq, off);
  if ((t & 63) == 0) red[t >> 6] = ssq;
  __syncthreads();
  if (t == 0) {
    x2[b] = red[0] + red[1] + red[2] + red[3];
    float s = sigma[b];
    inv2s2[b] = 1.0f / (2.0f * s * s);
  }
}

// ---------------------------------------------------------------------------
// prep_y: 64 rows/block. Writes yhi, ylo, y2, AND yT (transposed yhi).
// ---------------------------------------------------------------------------
__global__ __launch_bounds__(256) void prep_y_kernel(
    const float* __restrict__ y, unsigned short* __restrict__ yhi,
    unsigned short* __restrict__ ylo, unsigned short* __restrict__ yT,
    float* __restrict__ y2) {
  const int n0 = blockIdx.x * 64;
  const int t = threadIdx.x;
  __shared__ unsigned short T[64][68];
  float ssq[4] = {0.f, 0.f, 0.f, 0.f};
  const int rb = t >> 4;        // 0..15
  const int c4 = (t & 15) * 4;  // 0..60
  const int dr = t >> 2;        // 0..63
  const int nb4 = (t & 3) * 16;

  for (int dp = 0; dp < 48; ++dp) {
    const int d0 = dp * 64;
#pragma unroll
    for (int it = 0; it < 4; ++it) {
      const int r = it * 16 + rb;
      const int n = n0 + r;
      f32x4 v = (n < NREAL) ? *(const f32x4*)(y + (size_t)n * DD + d0 + c4)
                            : (f32x4){0.f, 0.f, 0.f, 0.f};
      u16x4 h, l;
#pragma unroll
      for (int j = 0; j < 4; ++j) {
        float f = v[j];
        ssq[it] += f * f;
        unsigned short hb = f32_bf16_rne(f);
        h[j] = hb;
        l[j] = f32_bf16_rne(f - bf16_f32(hb));
      }
      *(u16x4*)(yhi + (size_t)n * DD + d0 + c4) = h;
      *(u16x4*)(ylo + (size_t)n * DD + d0 + c4) = l;
      *(u16x4*)(&T[r][c4]) = h;
    }
    __syncthreads();
#pragma unroll
    for (int k = 0; k < 2; ++k) {
      const int nbb = nb4 + k * 8;
      u16x8 o;
#pragma unroll
      for (int j = 0; j < 8; ++j) o[j] = T[nbb + j][dr];
      *(u16x8*)(yT + (size_t)(d0 + dr) * NP + n0 + nbb) = o;
    }
    __syncthreads();
  }
#pragma unroll
  for (int it = 0; it < 4; ++it) {
    float s = ssq[it];
#pragma unroll
    for (int o = 8; o > 0; o >>= 1) s += __shfl_xor(s, o, 16);
    if ((t & 15) == 0) y2[n0 + it * 16 + rb] = s;
  }
}

// ---------------------------------------------------------------------------
// QK: 128x128 tile, BK=32, 32x32x16 MFMA, dbuf, vmcnt(8), stage-before-MFMA.
// LDS[row][p] holds global chunk p ^ ((row>>1)&3); read applies same XOR.
// ---------------------------------------------------------------------------
__global__ __launch_bounds__(256) void qk_kernel(
    const unsigned short* __restrict__ yhi, const unsigned short* __restrict__ ylo,
    const unsigned short* __restrict__ xhi, const unsigned short* __restrict__ xlo,
    const float* __restrict__ x2, const float* __restrict__ inv2s2,
    const float* __restrict__ y2, float* __restrict__ S) {
  const int orig = blockIdx.x;
  const int virt = (orig & 7) * 196 + (orig >> 3);  // 1568 = 8*196
  const int mt = virt & 3, nt = virt >> 2;
  const int m0 = mt * 128, n0 = nt * 128;
  const int t = threadIdx.x;
  const int lane = t & 63, w = t >> 6;
  const int wrow = w >> 1, wcol = w & 1;
  const int l31 = lane & 31, lh = lane >> 5;
  const int q = (lane >> 1) & 3;

  __shared__ __align__(16) unsigned short L[2 * 16384];  // 64 KB

  f32x16 acc[2][2] = {};

  const int srow = t >> 2;
  const int schunk = ((t & 3) ^ ((t >> 3) & 3)) * 8;
  const int sdst = t * 8;

  const unsigned short* pAh0 = xhi + (size_t)(m0 + srow) * DD + schunk;
  const unsigned short* pAh1 = xhi + (size_t)(m0 + srow + 64) * DD + schunk;
  const unsigned short* pAl0 = xlo + (size_t)(m0 + srow) * DD + schunk;
  const unsigned short* pAl1 = xlo + (size_t)(m0 + srow + 64) * DD + schunk;
  const unsigned short* pBh0 = yhi + (size_t)(n0 + srow) * DD + schunk;
  const unsigned short* pBh1 = yhi + (size_t)(n0 + srow + 64) * DD + schunk;
  const unsigned short* pBl0 = ylo + (size_t)(n0 + srow) * DD + schunk;
  const unsigned short* pBl1 = ylo + (size_t)(n0 + srow + 64) * DD + schunk;

  const int rowA = (wrow * 64 + l31) * 32;
  const int rowB = (wcol * 64 + l31) * 32;
  const int cof0 = (lh ^ q) * 8;        // k-half s=0
  const int cof1 = ((2 + lh) ^ q) * 8;  // k-half s=1

  auto STAGE = [&](int buf) {
    unsigned short* base = L + buf * 16384;
    gload16(pAh0, base + sdst);
    gload16(pAh1, base + sdst + 2048);
    gload16(pAl0, base + 4096 + sdst);
    gload16(pAl1, base + 4096 + sdst + 2048);
    gload16(pBh0, base + 8192 + sdst);
    gload16(pBh1, base + 8192 + sdst + 2048);
    gload16(pBl0, base + 12288 + sdst);
    gload16(pBl1, base + 12288 + sdst + 2048);
    pAh0 += 32; pAh1 += 32; pAl0 += 32; pAl1 += 32;
    pBh0 += 32; pBh1 += 32; pBl0 += 32; pBl1 += 32;
  };

  auto BODY = [&](int buf, bool do_stage) {
    const unsigned short* base = L + buf * 16384;
    bf16x8 ah[2][2], al[2][2], bh[2][2], bl[2][2];
#pragma unroll
    for (int fm = 0; fm < 2; ++fm) {
      const int o0 = rowA + fm * 1024;
      ah[fm][0] = ldsld(base + o0 + cof0);
      ah[fm][1] = ldsld(base + o0 + cof1);
      al[fm][0] = ldsld(base + 4096 + o0 + cof0);
      al[fm][1] = ldsld(base + 4096 + o0 + cof1);
    }
#pragma unroll
    for (int fn = 0; fn < 2; ++fn) {
      const int o0 = rowB + fn * 1024;
      bh[fn][0] = ldsld(base + 8192 + o0 + cof0);
      bh[fn][1] = ldsld(base + 8192 + o0 + cof1);
      bl[fn][0] = ldsld(base + 12288 + o0 + cof0);
      bl[fn][1] = ldsld(base + 12288 + o0 + cof1);
    }
    LGKM0;
    BAR;               // all waves done reading this buffer
    if (do_stage) STAGE(buf);
    SCHED0;            // keep gloads ahead of the MFMA cluster
    __builtin_amdgcn_s_setprio(1);
#pragma unroll
    for (int s = 0; s < 2; ++s)
#pragma unroll
      for (int fm = 0; fm < 2; ++fm)
#pragma unroll
        for (int fn = 0; fn < 2; ++fn) {
          acc[fm][fn] = __builtin_amdgcn_mfma_f32_32x32x16_bf16(ah[fm][s], bh[fn][s], acc[fm][fn], 0, 0, 0);
          acc[fm][fn] = __builtin_amdgcn_mfma_f32_32x32x16_bf16(ah[fm][s], bl[fn][s], acc[fm][fn], 0, 0, 0);
          acc[fm][fn] = __builtin_amdgcn_mfma_f32_32x32x16_bf16(al[fm][s], bh[fn][s], acc[fm][fn], 0, 0, 0);
        }
    __builtin_amdgcn_s_setprio(0);
  };

  STAGE(0);
  STAGE(1);
  for (int ks = 0; ks < 94; ++ks) {
    WAIT8; BAR;
    BODY(ks & 1, true);
  }
  WAIT8; BAR;
  BODY(0, false);
  WAIT0; BAR;
  BODY(1, false);

  // epilogue: logits
#pragma unroll
  for (int fn = 0; fn < 2; ++fn) {
    const int col = n0 + wcol * 64 + fn * 32 + l31;
    const bool ok = (col < NREAL);
    const float yy = ok ? y2[col] : 0.f;
#pragma unroll
    for (int fm = 0; fm < 2; ++fm) {
#pragma unroll
      for (int i = 0; i < 16; ++i) {
        const int row = m0 + wrow * 64 + fm * 32 + (i & 3) + 8 * (i >> 2) + 4 * lh;
        float v;
        if (ok) {
          float d2 = fmaxf(x2[row] + yy - 2.0f * acc[fm][fn][i], 0.0f);
          v = -d2 * inv2s2[row];
        } else {
          v = -3.0e38f;
        }
        S[(size_t)row * NP + col] = v;
      }
    }
  }
}

// ---------------------------------------------------------------------------
// softmax: 2 passes (max; exp+sum+write unnormalized bf16 P'), invs[b]=1/sum.
// ---------------------------------------------------------------------------
__global__ __launch_bounds__(256) void softmax_kernel(
    const float* __restrict__ S, unsigned short* __restrict__ P,
    float* __restrict__ invs) {
  const int b = blockIdx.x, t = threadIdx.x;
  const f32x4* row = (const f32x4*)(S + (size_t)b * NP);
  __shared__ float red[4];

  float m = -3.4e38f;
#pragma unroll 4
  for (int i = 0; i < 49; ++i) {
    f32x4 v = row[i * 256 + t];
    m = fmaxf(m, fmaxf(fmaxf(v[0], v[1]), fmaxf(v[2], v[3])));
  }
#pragma unroll
  for (int off = 32; off > 0; off >>= 1) m = fmaxf(m, __shfl_xor(m, off));
  if ((t & 63) == 0) red[t >> 6] = m;
  __syncthreads();
  m = fmaxf(fmaxf(red[0], red[1]), fmaxf(red[2], red[3]));
  __syncthreads();

  unsigned short* pr = P + (size_t)b * NP;
  float sum = 0.f;
#pragma unroll 4
  for (int i = 0; i < 49; ++i) {
    const int e = i * 256 + t;
    f32x4 v = row[e];
    float e0 = __expf(v[0] - m), e1 = __expf(v[1] - m);
    float e2 = __expf(v[2] - m), e3 = __expf(v[3] - m);
    sum += e0 + e1 + e2 + e3;
    u16x4 o;
    o[0] = f32_bf16_rne(e0); o[1] = f32_bf16_rne(e1);
    o[2] = f32_bf16_rne(e2); o[3] = f32_bf16_rne(e3);
    *(u16x4*)(pr + (size_t)e * 4) = o;
  }
#pragma unroll
  for (int off = 32; off > 0; off >>= 1) sum += __shfl_xor(sum, off);
  if ((t & 63) == 0) red[t >> 6] = sum;
  __syncthreads();
  if (t == 0) invs[b] = 1.0f / (red[0] + red[1] + red[2] + red[3]);
}

// ---------------------------------------------------------------------------
// PV: out = (P' @ yT^T) * invs. 128x128, BK=64, 32x32x16, dbuf, vmcnt(8),
// split-K=8, fp32 atomics.
// ---------------------------------------------------------------------------
__global__ __launch_bounds__(256) void pv_kernel(
    const unsigned short* __restrict__ yT, const unsigned short* __restrict__ P,
    const float* __restrict__ invs, float* __restrict__ out) {
  const int orig = blockIdx.x;
  const int virt = (orig & 7) * 96 + (orig >> 3);  // 768 = 8*96
  const int dt = virt % 24;
  const int mt = (virt / 24) & 3;
  const int sp = virt / 96;
  const int m0 = mt * 128, d0 = dt * 128;
  const int kbeg = sp * 6272;  // 98 steps of 64

  const int t = threadIdx.x, lane = t & 63, w = t >> 6;
  const int wrow = w >> 1, wcol = w & 1;
  const int l31 = lane & 31, lh = lane >> 5;
  const int q = (lane >> 1) & 3;

  __shared__ __align__(16) unsigned short L[2 * 16384];  // 64 KB

  f32x16 acc[2][2] = {};

  const int srow8 = t >> 3;                          // 0..31
  const int schunk = ((t & 7) ^ ((t >> 4) & 3)) * 8; // 8 chunks/row, XOR low2
  const int sdst = t * 8;

  const unsigned short* pA0 = P + (size_t)(m0 + srow8) * NP + kbeg + schunk;
  const unsigned short* pA1 = P + (size_t)(m0 + srow8 + 32) * NP + kbeg + schunk;
  const unsigned short* pA2 = P + (size_t)(m0 + srow8 + 64) * NP + kbeg + schunk;
  const unsigned short* pA3 = P + (size_t)(m0 + srow8 + 96) * NP + kbeg + schunk;
  const unsigned short* pB0 = yT + (size_t)(d0 + srow8) * NP + kbeg + schunk;
  const unsigned short* pB1 = yT + (size_t)(d0 + srow8 + 32) * NP + kbeg + schunk;
  const unsigned short* pB2 = yT + (size_t)(d0 + srow8 + 64) * NP + kbeg + schunk;
  const unsigned short* pB3 = yT + (size_t)(d0 + srow8 + 96) * NP + kbeg + schunk;

  const int rowA = (wrow * 64 + l31) * 64;
  const int rowB = (wcol * 64 + l31) * 64;
  // chunk offset for (slice sl, k-half s): p = sl*4 + ((s*2+lh)^q)
  const int cof[2][2] = {
    { ((lh ^ q)) * 8,       (((2 + lh) ^ q)) * 8 },
    { (4 + (lh ^ q)) * 8,   (4 + ((2 + lh) ^ q)) * 8 }
  };

  auto STAGE = [&](int buf) {
    unsigned short* base = L + buf * 16384;
    gload16(pA0, base + sdst);
    gload16(pA1, base + sdst + 2048);
    gload16(pA2, base + sdst + 4096);
    gload16(pA3, base + sdst + 6144);
    gload16(pB0, base + 8192 + sdst);
    gload16(pB1, base + 8192 + sdst + 2048);
    gload16(pB2, base + 8192 + sdst + 4096);
    gload16(pB3, base + 8192 + sdst + 6144);
    pA0 += 64; pA1 += 64; pA2 += 64; pA3 += 64;
    pB0 += 64; pB1 += 64; pB2 += 64; pB3 += 64;
  };

  auto BODY = [&](int buf, bool do_stage) {
    const unsigned short* base = L + buf * 16384;
    bf16x8 a[2][2][2], bv[2][2][2];
#pragma unroll
    for (int fm = 0; fm < 2; ++fm) {
      const int o0 = rowA + fm * 2048;
#pragma unroll
      for (int sl = 0; sl < 2; ++sl) {
        a[fm][sl][0] = ldsld(base + o0 + cof[sl][0]);
        a[fm][sl][1] = ldsld(base + o0 + cof[sl][1]);
      }
    }
#pragma unroll
    for (int fn = 0; fn < 2; ++fn) {
      const int o0 = rowB + fn * 2048;
#pragma unroll
      for (int sl = 0; sl < 2; ++sl) {
        bv[fn][sl][0] = ldsld(base + 8192 + o0 + cof[sl][0]);
        bv[fn][sl][1] = ldsld(base + 8192 + o0 + cof[sl][1]);
      }
    }
    LGKM0;
    BAR;
    if (do_stage) STAGE(buf);
    SCHED0;
    __builtin_amdgcn_s_setprio(1);
#pragma unroll
    for (int sl = 0; sl < 2; ++sl)
#pragma unroll
      for (int s = 0; s < 2; ++s)
#pragma unroll
        for (int fm = 0; fm < 2; ++fm)
#pragma unroll
          for (int fn = 0; fn < 2; ++fn)
            acc[fm][fn] = __builtin_amdgcn_mfma_f32_32x32x16_bf16(
                a[fm][sl][s], bv[fn][sl][s], acc[fm][fn], 0, 0, 0);
    __builtin_amdgcn_s_setprio(0);
  };

  STAGE(0);
  STAGE(1);
  for (int ks = 0; ks < 96; ++ks) {
    WAIT8; BAR;
    BODY(ks & 1, true);
  }
  WAIT8; BAR;
  BODY(0, false);
  WAIT0; BAR;
  BODY(1, false);

#pragma unroll
  for (int fm = 0; fm < 2; ++fm)
#pragma unroll
    for (int fn = 0; fn < 2; ++fn) {
      const int col = d0 + wcol * 64 + fn * 32 + l31;
#pragma unroll
      for (int i = 0; i < 16; ++i) {
        const int row = m0 + wrow * 64 + fm * 32 + (i & 3) + 8 * (i >> 2) + 4 * lh;
        unsafeAtomicAdd(out + (size_t)row * DD + col, acc[fm][fn][i] * invs[row]);
      }
    }
}

// ---------------------------------------------------------------------------
extern "C" void kernel_launch(void* const* d_in, const int* in_sizes, int n_in,
                              void* d_out, int out_size, void* d_ws, size_t ws_size,
                              hipStream_t stream) {
  const float* x = (const float*)d_in[0];
  const float* sigma = (const float*)d_in[1];
  const float* y = (const float*)d_in[2];
  float* out = (float*)d_out;
  char* ws = (char*)d_ws;

  size_t off = 0;
  float* S = (float*)(ws + off);                      off += (size_t)BB * NP * 4;
  unsigned short* yhi = (unsigned short*)(ws + off);  off += (size_t)NP * DD * 2;
  unsigned short* ylo = (unsigned short*)(ws + off);  off += (size_t)NP * DD * 2;
  unsigned short* P = ylo;  // ylo dead after QK; softmax writes P' here
  unsigned short* xhi = (unsigned short*)(ws + off);  off += (size_t)BB * DD * 2;
  unsigned short* xlo = (unsigned short*)(ws + off);  off += (size_t)BB * DD * 2;
  float* y2 = (float*)(ws + off);                     off += (size_t)NP * 4;
  float* x2 = (float*)(ws + off);                     off += 512 * 4;
  float* inv2s2 = (float*)(ws + off);                 off += 512 * 4;
  float* invs = (float*)(ws + off);                   off += 512 * 4;
  unsigned short* yT = (unsigned short*)(ws + off);   off += (size_t)DD * NP * 2;
  if (ws_size < off) return;  // harness provided >= this in rounds 2-3

  zero_kernel<<<dim3(1536), dim3(256), 0, stream>>>((f32x4*)out);
  prep_x_kernel<<<dim3(512), dim3(256), 0, stream>>>(x, sigma, xhi, xlo, x2, inv2s2);
  prep_y_kernel<<<dim3(NP / 64), dim3(256), 0, stream>>>(y, yhi, ylo, yT, y2);
  qk_kernel<<<dim3(1568), dim3(256), 0, stream>>>(yhi, ylo, xhi, xlo, x2, inv2s2, y2, S);
  softmax_kernel<<<dim3(512), dim3(256), 0, stream>>>(S, P, invs);
  pv_kernel<<<dim3(768), dim3(256), 0, stream>>>(yT, P, invs, out);
}